// Round 3
// baseline (699.682 us; speedup 1.0000x reference)
//
#include <hip/hip_runtime.h>
#include <hip/hip_bf16.h>

#define IN_F   4096
#define OUT_F  4096
#define NTOK   8192
#define LRANK  128

typedef unsigned short u16;
typedef __attribute__((ext_vector_type(8))) __bf16 bf16x8;
typedef __attribute__((ext_vector_type(4))) float f32x4;

__device__ __forceinline__ u16 f2bf(float f) {
  union { float f; unsigned u; } a; a.f = f;
  return (u16)((a.u + 0x7fffu + ((a.u >> 16) & 1u)) >> 16);
}

// async global->LDS, 16B per lane. LDS dest is wave-uniform base + lane*16.
__device__ __forceinline__ void async_ld16(const void* g, void* l) {
  __builtin_amdgcn_global_load_lds(
      (__attribute__((address_space(1))) void*)(unsigned long long)g,
      (__attribute__((address_space(3))) void*)(unsigned int)(unsigned long long)l,
      16, 0, 0);
}

// Stage one half-tile: 128 rows x 64 cols bf16 of row-major [*,stride] matrix
// into a 16 KiB LDS region, XOR-swizzled (T2) via pre-permuted GLOBAL source:
// dest chunk (row, slot) receives logical chunk (row, slot ^ (row&7)).
// 512 threads x 2 loads x 16B. LDS dest = wave-uniform base + lane*16.
__device__ __forceinline__ void stage_half(const u16* __restrict__ g, int stride,
                                           int row0, int col0, u16* ldsb, int tid) {
#pragma unroll
  for (int p = 0; p < 2; ++p) {
    int cbase = (tid & ~63) + (p << 9);       // wave-uniform chunk base
    int c = cbase + (tid & 63);               // chunk in [0,1024)
    int row = c >> 3, slot = c & 7;
    const u16* src = g + (size_t)(row0 + row) * stride + col0 + ((slot ^ (row & 7)) << 3);
    async_ld16(src, (char*)ldsb + (size_t)cbase * 16);
  }
}

// Swizzled frag read from a [128][64] bf16 half-tile region.
// logical: row r, k-slice ks (0/1), lane's 8 elems at k = ks*32+(lane>>4)*8.
__device__ __forceinline__ bf16x8 ld_frag(const u16* half_base, int r, int ks, int lane) {
  int byte = (r << 7) + (ks << 6) + ((lane >> 4) << 4);
  byte ^= (r & 7) << 4;
  return *(const bf16x8*)((const char*)half_base + byte);
}

// ---------------- prep kernels ----------------

__global__ void cvt_bf16_kernel(const float* __restrict__ src, u16* __restrict__ dst, int n4) {
  int i = blockIdx.x * blockDim.x + threadIdx.x;
  if (i >= n4) return;
  float4 v = ((const float4*)src)[i];
  ushort4 o;
  o.x = f2bf(v.x); o.y = f2bf(v.y); o.z = f2bf(v.z); o.w = f2bf(v.w);
  ((ushort4*)dst)[i] = o;
}

__global__ void dequant_kernel(const int* __restrict__ zm, const float* __restrict__ cb,
                               const float* __restrict__ gs, const float* __restrict__ gb,
                               u16* __restrict__ W) {
  int idx = blockIdx.x * blockDim.x + threadIdx.x;   // one thread per 4 weights
  if (idx >= OUT_F * IN_F / 4) return;
  int o = idx >> 10;
  int i = (idx & 1023) << 2;
  int row = ((o >> 6) << 6) + (i >> 6);
  const int* zp = zm + ((size_t)row << 12) + ((o & 63) << 6) + (i & 63);
  int4 z = *(const int4*)zp;
  const float* cr = cb + ((size_t)row << 8);
  int g = (o >> 3) * (IN_F / 8) + (i >> 3);
  float s = gs[g], b = gb[g];
  ushort4 w;
  w.x = f2bf(b + cr[z.x] * s);
  w.y = f2bf(b + cr[z.y] * s);
  w.z = f2bf(b + cr[z.z] * s);
  w.w = f2bf(b + cr[z.w] * s);
  *(ushort4*)(W + (size_t)idx * 4) = w;
}

// ---------------- hid GEMM (unchanged, correct) ----------------

__device__ __forceinline__ void stage_tile_128x32(const u16* __restrict__ g, int stride,
                                                  int row0, int col0,
                                                  u16* lbase, int wave, int lane) {
#pragma unroll
  for (int p = 0; p < 2; ++p) {
    int li_base = wave * 64 + p * 256;
    int li = li_base + lane;
    const u16* gaddr = g + (size_t)(row0 + (li >> 2)) * stride + col0 + ((li & 3) << 3);
    async_ld16(gaddr, lbase + li_base * 8);
  }
}

__global__ __launch_bounds__(256) void gemm_hid(const u16* __restrict__ A,
                                                const u16* __restrict__ L1,
                                                u16* __restrict__ H) {
  __shared__ __align__(16) u16 lds[2 * 128 * 32];
  u16* ldsA = lds;
  u16* ldsB = lds + 128 * 32;

  int tid = threadIdx.x;
  int wave = tid >> 6, lane = tid & 63;
  int bm0 = blockIdx.x * 128;
  int wr = (wave >> 1) * 64, wc = (wave & 1) * 64;
  int lrow = lane & 15, lk = (lane >> 4) * 8;

  f32x4 acc[4][4];
#pragma unroll
  for (int m = 0; m < 4; ++m)
#pragma unroll
    for (int n = 0; n < 4; ++n)
#pragma unroll
      for (int v = 0; v < 4; ++v) acc[m][n][v] = 0.f;

  for (int kt = 0; kt < IN_F / 32; ++kt) {
    int k0 = kt * 32;
    stage_tile_128x32(A, IN_F, bm0, k0, ldsA, wave, lane);
    stage_tile_128x32(L1, IN_F, 0, k0, ldsB, wave, lane);
    __syncthreads();
    bf16x8 af[4], bfr[4];
#pragma unroll
    for (int m = 0; m < 4; ++m)
      af[m] = *(const bf16x8*)&ldsA[(wr + m * 16 + lrow) * 32 + lk];
#pragma unroll
    for (int n = 0; n < 4; ++n)
      bfr[n] = *(const bf16x8*)&ldsB[(wc + n * 16 + lrow) * 32 + lk];
#pragma unroll
    for (int m = 0; m < 4; ++m)
#pragma unroll
      for (int n = 0; n < 4; ++n)
        acc[m][n] = __builtin_amdgcn_mfma_f32_16x16x32_bf16(af[m], bfr[n], acc[m][n], 0, 0, 0);
    __syncthreads();
  }

  int lrow4 = (lane >> 4) * 4;
#pragma unroll
  for (int m = 0; m < 4; ++m)
#pragma unroll
    for (int n = 0; n < 4; ++n)
#pragma unroll
      for (int v = 0; v < 4; ++v) {
        int rg = bm0 + wr + m * 16 + lrow4 + v;
        int cg = wc + n * 16 + lrow;
        H[(size_t)rg * LRANK + cg] = f2bf(acc[m][n][v]);
      }
}

// ---------------- main GEMM: 256x256 tile, BK=64, 8-phase schedule ----------------
// buf0 holds even K-tiles, buf1 odd. Stage ledger (per iter u; kt c0=2u, c1=2u+1,
// n0=2u+2, n1=2u+3):  P1: buf1.A-h0<-c1  P2: buf1.A-h1<-c1  P3: buf0.B-h0<-n0
// P4: buf0.B-h1<-n0 +vmcnt(4)  P5: buf0.A-h0<-n0  P6: buf0.A-h1<-n0
// P7: buf1.B-h0<-n1  P8: buf1.B-h1<-n1 +vmcnt(4).
// Deadness: B dies after phase 2/6 (nh0 kept in regs), A after 3/7.

#define MFMA_QUAD(mh, nh)                                                        \
  _Pragma("unroll") for (int mf = 0; mf < 4; ++mf)                               \
  _Pragma("unroll") for (int nf = 0; nf < 2; ++nf)                               \
  _Pragma("unroll") for (int ks = 0; ks < 2; ++ks)                               \
    acc[(mh)*4 + mf][(nh)*2 + nf] = __builtin_amdgcn_mfma_f32_16x16x32_bf16(     \
        af[mf][ks], bfr[nh][nf][ks], acc[(mh)*4 + mf][(nh)*2 + nf], 0, 0, 0);

#define PHASE_MID                                          \
  __builtin_amdgcn_s_barrier();                            \
  asm volatile("s_waitcnt lgkmcnt(0)" ::: "memory");       \
  __builtin_amdgcn_sched_barrier(0);                       \
  __builtin_amdgcn_s_setprio(1);

#define PHASE_END                                          \
  __builtin_amdgcn_s_setprio(0);                           \
  __builtin_amdgcn_s_barrier();

#define PHASE_END_VM                                       \
  __builtin_amdgcn_s_setprio(0);                           \
  asm volatile("s_waitcnt vmcnt(4)" ::: "memory");         \
  __builtin_amdgcn_s_barrier();

__global__ __launch_bounds__(512, 2) void gemm_main(const u16* __restrict__ A,
                                                    const u16* __restrict__ W,
                                                    const u16* __restrict__ H,
                                                    const u16* __restrict__ L2,
                                                    const float* __restrict__ scale,
                                                    const float* __restrict__ bias,
                                                    float* __restrict__ out) {
  __shared__ __align__(16) u16 lds[65536];   // 128 KiB

  const int tid = threadIdx.x;
  const int lane = tid & 63, wave = tid >> 6;
  const int wg_m = wave >> 2, wg_n = wave & 3;
  const int lr = lane & 15;

  // bijective XCD swizzle (nwg=512, 512%8==0)
  int bid = blockIdx.x;
  int swz = (bid & 7) * 64 + (bid >> 3);
  const int bn0 = (swz & 15) * 256;
  const int bm0 = (swz >> 4) * 256;

  // LDS regions (u16 units): buf b at b*32768; A halves +0,+8192; B halves +16384,+24576
#define LA(b, h) (lds + (b) * 32768 + (h) * 8192)
#define LB(b, h) (lds + (b) * 32768 + 16384 + (h) * 8192)

  const int b_half = wg_n >> 1;            // wave's B storage half
  const int b_row0 = (wg_n & 1) * 64;      // row base within that half

  f32x4 acc[8][4];
#pragma unroll
  for (int m = 0; m < 8; ++m)
#pragma unroll
    for (int n = 0; n < 4; ++n)
#pragma unroll
      for (int v = 0; v < 4; ++v) acc[m][n][v] = 0.f;

  // ---- prologue: kt0 -> buf0 (B0,B1,A0,A1), kt1.B -> buf1 ----
  stage_half(W, IN_F, bn0 + 0,   0, LB(0, 0), tid);
  stage_half(W, IN_F, bn0 + 128, 0, LB(0, 1), tid);
  stage_half(A, IN_F, bm0 + 0,   0, LA(0, 0), tid);
  stage_half(A, IN_F, bm0 + 128, 0, LA(0, 1), tid);
  stage_half(W, IN_F, bn0 + 0,   64, LB(1, 0), tid);
  stage_half(W, IN_F, bn0 + 128, 64, LB(1, 1), tid);
  asm volatile("s_waitcnt vmcnt(4)" ::: "memory");   // kt0 landed; kt1.B may fly
  __builtin_amdgcn_s_barrier();

  bf16x8 af[4][2];        // current A m-half (4 m-frags x 2 k-slices)
  bf16x8 bfr[2][2][2];    // both B n-halves kept ([nh][nf][ks])

  for (int u = 0; u < 32; ++u) {
    const int c1k = (2 * u + 1) * 64;
    const int n0  = 2 * u + 2, n1 = 2 * u + 3;
    const int n0k = (n0 > 63 ? 63 : n0) * 64;
    const int n1k = (n1 > 63 ? 63 : n1) * 64;

    // ---- P1: quad(0,0) on buf0 ----
#pragma unroll
    for (int mf = 0; mf < 4; ++mf)
#pragma unroll
      for (int ks = 0; ks < 2; ++ks)
        af[mf][ks] = ld_frag(LA(0, wg_m), mf * 16 + lr, ks, lane);
#pragma unroll
    for (int nf = 0; nf < 2; ++nf)
#pragma unroll
      for (int ks = 0; ks < 2; ++ks)
        bfr[0][nf][ks] = ld_frag(LB(0, b_half), b_row0 + nf * 16 + lr, ks, lane);
    stage_half(A, IN_F, bm0 + 0, c1k, LA(1, 0), tid);
    PHASE_MID; MFMA_QUAD(0, 0); PHASE_END;

    // ---- P2: quad(0,1) ----
#pragma unroll
    for (int nf = 0; nf < 2; ++nf)
#pragma unroll
      for (int ks = 0; ks < 2; ++ks)
        bfr[1][nf][ks] = ld_frag(LB(0, b_half), b_row0 + 32 + nf * 16 + lr, ks, lane);
    stage_half(A, IN_F, bm0 + 128, c1k, LA(1, 1), tid);
    PHASE_MID; MFMA_QUAD(0, 1); PHASE_END;

    // ---- P3: quad(1,1) ----
#pragma unroll
    for (int mf = 0; mf < 4; ++mf)
#pragma unroll
      for (int ks = 0; ks < 2; ++ks)
        af[mf][ks] = ld_frag(LA(0, wg_m), 64 + mf * 16 + lr, ks, lane);
    stage_half(W, IN_F, bn0 + 0, n0k, LB(0, 0), tid);
    PHASE_MID; MFMA_QUAD(1, 1); PHASE_END;

    // ---- P4: quad(1,0) (all regs) ----
    stage_half(W, IN_F, bn0 + 128, n0k, LB(0, 1), tid);
    PHASE_MID; MFMA_QUAD(1, 0); PHASE_END_VM;

    // ---- P5: quad(0,0) on buf1 ----
#pragma unroll
    for (int mf = 0; mf < 4; ++mf)
#pragma unroll
      for (int ks = 0; ks < 2; ++ks)
        af[mf][ks] = ld_frag(LA(1, wg_m), mf * 16 + lr, ks, lane);
#pragma unroll
    for (int nf = 0; nf < 2; ++nf)
#pragma unroll
      for (int ks = 0; ks < 2; ++ks)
        bfr[0][nf][ks] = ld_frag(LB(1, b_half), b_row0 + nf * 16 + lr, ks, lane);
    stage_half(A, IN_F, bm0 + 0, n0k, LA(0, 0), tid);
    PHASE_MID; MFMA_QUAD(0, 0); PHASE_END;

    // ---- P6: quad(0,1) ----
#pragma unroll
    for (int nf = 0; nf < 2; ++nf)
#pragma unroll
      for (int ks = 0; ks < 2; ++ks)
        bfr[1][nf][ks] = ld_frag(LB(1, b_half), b_row0 + 32 + nf * 16 + lr, ks, lane);
    stage_half(A, IN_F, bm0 + 128, n0k, LA(0, 1), tid);
    PHASE_MID; MFMA_QUAD(0, 1); PHASE_END;

    // ---- P7: quad(1,1) ----
#pragma unroll
    for (int mf = 0; mf < 4; ++mf)
#pragma unroll
      for (int ks = 0; ks < 2; ++ks)
        af[mf][ks] = ld_frag(LA(1, wg_m), 64 + mf * 16 + lr, ks, lane);
    stage_half(W, IN_F, bn0 + 0, n1k, LB(1, 0), tid);
    PHASE_MID; MFMA_QUAD(1, 1); PHASE_END;

    // ---- P8: quad(1,0) (all regs) ----
    stage_half(W, IN_F, bn0 + 128, n1k, LB(1, 1), tid);
    PHASE_MID; MFMA_QUAD(1, 0); PHASE_END_VM;
  }

  // ---- drain outstanding stages before LDS reuse ----
  asm volatile("s_waitcnt vmcnt(0)" ::: "memory");
  __builtin_amdgcn_s_barrier();

  // ---- fused low-rank epilogue ----
  float scl[4], bs_[4];
#pragma unroll
  for (int nf = 0; nf < 4; ++nf) {
    int cg = bn0 + wg_n * 64 + nf * 16 + lr;
    scl[nf] = scale[cg];
    bs_[nf] = bias[cg];
  }

  // regions: H col-subtile s: lds + s*16384 (+8192 for rows 128-255)
  //          L2 col-subtile s: lds + 32768 + s*16384
  stage_half(H, LRANK, bm0 + 0,   0,  lds + 0,     tid);
  stage_half(H, LRANK, bm0 + 128, 0,  lds + 8192,  tid);
  stage_half(H, LRANK, bm0 + 0,   64, lds + 16384, tid);
  stage_half(H, LRANK, bm0 + 128, 64, lds + 24576, tid);
  stage_half(L2, LRANK, bn0 + 0,   0,  lds + 32768, tid);
  stage_half(L2, LRANK, bn0 + 128, 0,  lds + 40960, tid);
  stage_half(L2, LRANK, bn0 + 0,   64, lds + 49152, tid);
  stage_half(L2, LRANK, bn0 + 128, 64, lds + 57344, tid);
  asm volatile("s_waitcnt vmcnt(0)" ::: "memory");
  __builtin_amdgcn_s_barrier();

  // multiplicative pass: acc *= (H·L2m + scale)
#pragma unroll
  for (int nh = 0; nh < 2; ++nh) {
    f32x4 macc[8][2];
#pragma unroll
    for (int m = 0; m < 8; ++m)
#pragma unroll
      for (int j = 0; j < 2; ++j)
#pragma unroll
        for (int v = 0; v < 4; ++v) macc[m][j][v] = 0.f;
#pragma unroll
    for (int kc = 0; kc < 4; ++kc) {
      const u16* Hb = lds + (kc >> 1) * 16384;
      const u16* Lb = lds + 32768 + (kc >> 1) * 16384;
      int ks = kc & 1;
      bf16x8 lf[2];
#pragma unroll
      for (int j = 0; j < 2; ++j) {
        int q = wg_n * 64 + (nh * 2 + j) * 16 + lr;
        lf[j] = ld_frag(Lb + (q >> 7) * 8192, q & 127, ks, lane);
      }
#pragma unroll
      for (int mf = 0; mf < 8; ++mf) {
        int q = wg_m * 128 + mf * 16 + lr;
        bf16x8 hf = ld_frag(Hb + (q >> 7) * 8192, q & 127, ks, lane);
        macc[mf][0] = __builtin_amdgcn_mfma_f32_16x16x32_bf16(hf, lf[0], macc[mf][0], 0, 0, 0);
        macc[mf][1] = __builtin_amdgcn_mfma_f32_16x16x32_bf16(hf, lf[1], macc[mf][1], 0, 0, 0);
      }
    }
#pragma unroll
    for (int mf = 0; mf < 8; ++mf)
#pragma unroll
      for (int j = 0; j < 2; ++j)
#pragma unroll
        for (int v = 0; v < 4; ++v)
          acc[mf][nh * 2 + j][v] *= (macc[mf][j][v] + scl[nh * 2 + j]);
  }

  // restage L2 additive rows
  __builtin_amdgcn_s_barrier();
  stage_half(L2, LRANK, OUT_F + bn0 + 0,   0,  lds + 32768, tid);
  stage_half(L2, LRANK, OUT_F + bn0 + 128, 0,  lds + 40960, tid);
  stage_half(L2, LRANK, OUT_F + bn0 + 0,   64, lds + 49152, tid);
  stage_half(L2, LRANK, OUT_F + bn0 + 128, 64, lds + 57344, tid);
  asm volatile("s_waitcnt vmcnt(0)" ::: "memory");
  __builtin_amdgcn_s_barrier();

  // additive pass: acc += H·L2a + bias
#pragma unroll
  for (int nh = 0; nh < 2; ++nh) {
    f32x4 macc[8][2];
#pragma unroll
    for (int m = 0; m < 8; ++m)
#pragma unroll
      for (int j = 0; j < 2; ++j)
#pragma unroll
        for (int v = 0; v < 4; ++v) macc[m][j][v] = 0.f;
#pragma unroll
    for (int kc = 0; kc < 4; ++kc) {
      const u16* Hb = lds + (kc >> 1) * 16384;
      const u16* Lb = lds + 32768 + (kc >> 1) * 16384;
      int ks = kc & 1;
      bf16x8 lf[2];
#pragma unroll
      for (int j = 0; j < 2; ++j) {
        int q = wg_n * 64 + (nh * 2 + j) * 16 + lr;
        lf[j] = ld_frag(Lb + (q >> 7) * 8192, q & 127, ks, lane);
      }
#pragma unroll
      for (int mf = 0; mf < 8; ++mf) {
        int q = wg_m * 128 + mf * 16 + lr;
        bf16x8 hf = ld_frag(Hb + (q >> 7) * 8192, q & 127, ks, lane);
        macc[mf][0] = __builtin_amdgcn_mfma_f32_16x16x32_bf16(hf, lf[0], macc[mf][0], 0, 0, 0);
        macc[mf][1] = __builtin_amdgcn_mfma_f32_16x16x32_bf16(hf, lf[1], macc[mf][1], 0, 0, 0);
      }
    }
#pragma unroll
    for (int mf = 0; mf < 8; ++mf)
#pragma unroll
      for (int j = 0; j < 2; ++j)
#pragma unroll
        for (int v = 0; v < 4; ++v)
          acc[mf][nh * 2 + j][v] += macc[mf][j][v] + bs_[nh * 2 + j];
  }

  // ---- store ----
#pragma unroll
  for (int mf = 0; mf < 8; ++mf)
#pragma unroll
    for (int nf = 0; nf < 4; ++nf)
#pragma unroll
      for (int v = 0; v < 4; ++v) {
        int rg = bm0 + wg_m * 128 + mf * 16 + (lane >> 4) * 4 + v;
        int cg = bn0 + wg_n * 64 + nf * 16 + lr;
        out[(size_t)rg * OUT_F + cg] = acc[mf][nf][v];
      }
}

// ---------------- launch ----------------

extern "C" void kernel_launch(void* const* d_in, const int* in_sizes, int n_in,
                              void* d_out, int out_size, void* d_ws, size_t ws_size,
                              hipStream_t stream) {
  const float* input = (const float*)d_in[0];
  const int*   zm    = (const int*)d_in[1];
  const float* cb    = (const float*)d_in[2];
  const float* l1    = (const float*)d_in[3];
  const float* l2    = (const float*)d_in[4];
  const float* gs    = (const float*)d_in[5];
  const float* gb    = (const float*)d_in[6];
  const float* scale = (const float*)d_in[7];
  const float* bias  = (const float*)d_in[8];
  float* out = (float*)d_out;

  const size_t OFF_A  = 0;                                        // 64 MiB
  const size_t OFF_W  = OFF_A + (size_t)NTOK * IN_F * 2;          // 32 MiB
  const size_t OFF_L1 = OFF_W + (size_t)OUT_F * IN_F * 2;         // 1 MiB
  const size_t OFF_L2 = OFF_L1 + (size_t)LRANK * IN_F * 2;        // 2 MiB
  const size_t OFF_H  = OFF_L2 + (size_t)2 * OUT_F * LRANK * 2;   // 2 MiB
  const size_t NEED   = OFF_H + (size_t)NTOK * LRANK * 2;
  if (ws_size < NEED) return;

  char* ws = (char*)d_ws;
  u16* A   = (u16*)(ws + OFF_A);
  u16* W   = (u16*)(ws + OFF_W);
  u16* L1b = (u16*)(ws + OFF_L1);
  u16* L2b = (u16*)(ws + OFF_L2);
  u16* H   = (u16*)(ws + OFF_H);

  cvt_bf16_kernel<<<(NTOK * IN_F / 4) / 256, 256, 0, stream>>>(input, A, NTOK * IN_F / 4);
  cvt_bf16_kernel<<<(LRANK * IN_F / 4) / 256, 256, 0, stream>>>(l1, L1b, LRANK * IN_F / 4);
  cvt_bf16_kernel<<<(2 * OUT_F * LRANK / 4) / 256, 256, 0, stream>>>(l2, L2b, 2 * OUT_F * LRANK / 4);
  dequant_kernel<<<(OUT_F * IN_F / 4) / 256, 256, 0, stream>>>(zm, cb, gs, gb, W);

  gemm_hid<<<NTOK / 128, 256, 0, stream>>>(A, L1b, H);

  gemm_main<<<(NTOK / 256) * (OUT_F / 256), 512, 0, stream>>>(A, W, H, L2b, scale, bias, out);
}

// Round 4
// 692.067 us; speedup vs baseline: 1.0110x; 1.0110x over previous
//
#include <hip/hip_runtime.h>
#include <hip/hip_bf16.h>

#define IN_F   4096
#define OUT_F  4096
#define NTOK   8192
#define LRANK  128

typedef unsigned short u16;
typedef __attribute__((ext_vector_type(8))) __bf16 bf16x8;
typedef __attribute__((ext_vector_type(4))) float f32x4;

__device__ __forceinline__ u16 f2bf(float f) {
  union { float f; unsigned u; } a; a.f = f;
  return (u16)((a.u + 0x7fffu + ((a.u >> 16) & 1u)) >> 16);
}

// async global->LDS, 16B per lane. LDS dest is wave-uniform base + lane*16.
__device__ __forceinline__ void async_ld16(const void* g, void* l) {
  __builtin_amdgcn_global_load_lds(
      (__attribute__((address_space(1))) void*)(unsigned long long)g,
      (__attribute__((address_space(3))) void*)(unsigned int)(unsigned long long)l,
      16, 0, 0);
}

// Stage one half-tile: 128 rows x 64 cols bf16 of row-major [*,stride] matrix
// into a 16 KiB LDS region, XOR-swizzled (T2) via pre-permuted GLOBAL source:
// dest chunk (row, slot) receives logical chunk (row, slot ^ (row&7)).
// 512 threads x 2 loads x 16B. LDS dest = wave-uniform base + lane*16.
__device__ __forceinline__ void stage_half(const u16* __restrict__ g, int stride,
                                           int row0, int col0, u16* ldsb, int tid) {
#pragma unroll
  for (int p = 0; p < 2; ++p) {
    int cbase = (tid & ~63) + (p << 9);       // wave-uniform chunk base
    int c = cbase + (tid & 63);               // chunk in [0,1024)
    int row = c >> 3, slot = c & 7;
    const u16* src = g + (size_t)(row0 + row) * stride + col0 + ((slot ^ (row & 7)) << 3);
    async_ld16(src, (char*)ldsb + (size_t)cbase * 16);
  }
}

// Swizzled frag read from a [128][64] bf16 half-tile region.
// logical: row r, k-slice ks (0/1), lane's 8 elems at k = ks*32+(lane>>4)*8.
__device__ __forceinline__ bf16x8 ld_frag(const u16* half_base, int r, int ks, int lane) {
  int byte = (r << 7) + (ks << 6) + ((lane >> 4) << 4);
  byte ^= (r & 7) << 4;
  return *(const bf16x8*)((const char*)half_base + byte);
}

// ---------------- prep kernels ----------------

__global__ void cvt_bf16_kernel(const float* __restrict__ src, u16* __restrict__ dst, int n4) {
  int i = blockIdx.x * blockDim.x + threadIdx.x;
  if (i >= n4) return;
  float4 v = ((const float4*)src)[i];
  ushort4 o;
  o.x = f2bf(v.x); o.y = f2bf(v.y); o.z = f2bf(v.z); o.w = f2bf(v.w);
  ((ushort4*)dst)[i] = o;
}

__global__ void dequant_kernel(const int* __restrict__ zm, const float* __restrict__ cb,
                               const float* __restrict__ gs, const float* __restrict__ gb,
                               u16* __restrict__ W) {
  int idx = blockIdx.x * blockDim.x + threadIdx.x;   // one thread per 4 weights
  if (idx >= OUT_F * IN_F / 4) return;
  int o = idx >> 10;
  int i = (idx & 1023) << 2;
  int row = ((o >> 6) << 6) + (i >> 6);
  const int* zp = zm + ((size_t)row << 12) + ((o & 63) << 6) + (i & 63);
  int4 z = *(const int4*)zp;
  const float* cr = cb + ((size_t)row << 8);
  int g = (o >> 3) * (IN_F / 8) + (i >> 3);
  float s = gs[g], b = gb[g];
  ushort4 w;
  w.x = f2bf(b + cr[z.x] * s);
  w.y = f2bf(b + cr[z.y] * s);
  w.z = f2bf(b + cr[z.z] * s);
  w.w = f2bf(b + cr[z.w] * s);
  *(ushort4*)(W + (size_t)idx * 4) = w;
}

// ---------------- hid GEMM (unchanged, correct) ----------------

__device__ __forceinline__ void stage_tile_128x32(const u16* __restrict__ g, int stride,
                                                  int row0, int col0,
                                                  u16* lbase, int wave, int lane) {
#pragma unroll
  for (int p = 0; p < 2; ++p) {
    int li_base = wave * 64 + p * 256;
    int li = li_base + lane;
    const u16* gaddr = g + (size_t)(row0 + (li >> 2)) * stride + col0 + ((li & 3) << 3);
    async_ld16(gaddr, lbase + li_base * 8);
  }
}

__global__ __launch_bounds__(256) void gemm_hid(const u16* __restrict__ A,
                                                const u16* __restrict__ L1,
                                                u16* __restrict__ H) {
  __shared__ __align__(16) u16 lds[2 * 128 * 32];
  u16* ldsA = lds;
  u16* ldsB = lds + 128 * 32;

  int tid = threadIdx.x;
  int wave = tid >> 6, lane = tid & 63;
  int bm0 = blockIdx.x * 128;
  int wr = (wave >> 1) * 64, wc = (wave & 1) * 64;
  int lrow = lane & 15, lk = (lane >> 4) * 8;

  f32x4 acc[4][4];
#pragma unroll
  for (int m = 0; m < 4; ++m)
#pragma unroll
    for (int n = 0; n < 4; ++n)
#pragma unroll
      for (int v = 0; v < 4; ++v) acc[m][n][v] = 0.f;

  for (int kt = 0; kt < IN_F / 32; ++kt) {
    int k0 = kt * 32;
    stage_tile_128x32(A, IN_F, bm0, k0, ldsA, wave, lane);
    stage_tile_128x32(L1, IN_F, 0, k0, ldsB, wave, lane);
    __syncthreads();
    bf16x8 af[4], bfr[4];
#pragma unroll
    for (int m = 0; m < 4; ++m)
      af[m] = *(const bf16x8*)&ldsA[(wr + m * 16 + lrow) * 32 + lk];
#pragma unroll
    for (int n = 0; n < 4; ++n)
      bfr[n] = *(const bf16x8*)&ldsB[(wc + n * 16 + lrow) * 32 + lk];
#pragma unroll
    for (int m = 0; m < 4; ++m)
#pragma unroll
      for (int n = 0; n < 4; ++n)
        acc[m][n] = __builtin_amdgcn_mfma_f32_16x16x32_bf16(af[m], bfr[n], acc[m][n], 0, 0, 0);
    __syncthreads();
  }

  int lrow4 = (lane >> 4) * 4;
#pragma unroll
  for (int m = 0; m < 4; ++m)
#pragma unroll
    for (int n = 0; n < 4; ++n)
#pragma unroll
      for (int v = 0; v < 4; ++v) {
        int rg = bm0 + wr + m * 16 + lrow4 + v;
        int cg = wc + n * 16 + lrow;
        H[(size_t)rg * LRANK + cg] = f2bf(acc[m][n][v]);
      }
}

// ---------------- main GEMM: 256x256 tile, BK=64, 8-phase schedule ----------------
// buf0 holds even K-tiles, buf1 odd. Stage ledger (per iter u; kt c0=2u, c1=2u+1,
// n0=2u+2, n1=2u+3):  P1: buf1.A-h0<-c1  P2: buf1.A-h1<-c1  P3: buf0.B-h0<-n0
// P4: buf0.B-h1<-n0 +vmcnt(4)  P5: buf0.A-h0<-n0  P6: buf0.A-h1<-n0
// P7: buf1.B-h0<-n1  P8: buf1.B-h1<-n1 +vmcnt(4).
// Deadness: B dies after phase 2/6 (nh0 kept in regs), A after 3/7.

#define MFMA_QUAD(mh, nh)                                                        \
  _Pragma("unroll") for (int mf = 0; mf < 4; ++mf)                               \
  _Pragma("unroll") for (int nf = 0; nf < 2; ++nf)                               \
  _Pragma("unroll") for (int ks = 0; ks < 2; ++ks)                               \
    acc[(mh)*4 + mf][(nh)*2 + nf] = __builtin_amdgcn_mfma_f32_16x16x32_bf16(     \
        af[mf][ks], bfr[nh][nf][ks], acc[(mh)*4 + mf][(nh)*2 + nf], 0, 0, 0);

#define PHASE_MID                                          \
  __builtin_amdgcn_s_barrier();                            \
  asm volatile("s_waitcnt lgkmcnt(0)" ::: "memory");       \
  __builtin_amdgcn_sched_barrier(0);                       \
  __builtin_amdgcn_s_setprio(1);

#define PHASE_END                                          \
  __builtin_amdgcn_s_setprio(0);                           \
  __builtin_amdgcn_s_barrier();

#define PHASE_END_VM                                       \
  __builtin_amdgcn_s_setprio(0);                           \
  asm volatile("s_waitcnt vmcnt(4)" ::: "memory");         \
  __builtin_amdgcn_s_barrier();

__global__ __launch_bounds__(512, 1) void gemm_main(const u16* __restrict__ A,
                                                    const u16* __restrict__ W,
                                                    const u16* __restrict__ H,
                                                    const u16* __restrict__ L2,
                                                    const float* __restrict__ scale,
                                                    const float* __restrict__ bias,
                                                    float* __restrict__ out) {
  __shared__ __align__(16) u16 lds[65536];   // 128 KiB

  const int tid = threadIdx.x;
  const int lane = tid & 63, wave = tid >> 6;
  const int wg_m = wave >> 2, wg_n = wave & 3;
  const int lr = lane & 15;

  // bijective XCD swizzle (nwg=512, 512%8==0)
  int bid = blockIdx.x;
  int swz = (bid & 7) * 64 + (bid >> 3);
  const int bn0 = (swz & 15) * 256;
  const int bm0 = (swz >> 4) * 256;

  // LDS regions (u16 units): buf b at b*32768; A halves +0,+8192; B halves +16384,+24576
#define LA(b, h) (lds + (b) * 32768 + (h) * 8192)
#define LB(b, h) (lds + (b) * 32768 + 16384 + (h) * 8192)

  const int b_half = wg_n >> 1;            // wave's B storage half
  const int b_row0 = (wg_n & 1) * 64;      // row base within that half

  f32x4 acc[8][4];
#pragma unroll
  for (int m = 0; m < 8; ++m)
#pragma unroll
    for (int n = 0; n < 4; ++n)
#pragma unroll
      for (int v = 0; v < 4; ++v) acc[m][n][v] = 0.f;

  // ---- prologue: kt0 -> buf0 (B0,B1,A0,A1), kt1.B -> buf1 ----
  stage_half(W, IN_F, bn0 + 0,   0, LB(0, 0), tid);
  stage_half(W, IN_F, bn0 + 128, 0, LB(0, 1), tid);
  stage_half(A, IN_F, bm0 + 0,   0, LA(0, 0), tid);
  stage_half(A, IN_F, bm0 + 128, 0, LA(0, 1), tid);
  stage_half(W, IN_F, bn0 + 0,   64, LB(1, 0), tid);
  stage_half(W, IN_F, bn0 + 128, 64, LB(1, 1), tid);
  asm volatile("s_waitcnt vmcnt(4)" ::: "memory");   // kt0 landed; kt1.B may fly
  __builtin_amdgcn_s_barrier();

  bf16x8 af[4][2];        // current A m-half (4 m-frags x 2 k-slices)
  bf16x8 bfr[2][2][2];    // both B n-halves kept ([nh][nf][ks])

  for (int u = 0; u < 32; ++u) {
    const int c1k = (2 * u + 1) * 64;
    const int n0  = 2 * u + 2, n1 = 2 * u + 3;
    const int n0k = (n0 > 63 ? 63 : n0) * 64;
    const int n1k = (n1 > 63 ? 63 : n1) * 64;

    // ---- P1: quad(0,0) on buf0 ----
#pragma unroll
    for (int mf = 0; mf < 4; ++mf)
#pragma unroll
      for (int ks = 0; ks < 2; ++ks)
        af[mf][ks] = ld_frag(LA(0, wg_m), mf * 16 + lr, ks, lane);
#pragma unroll
    for (int nf = 0; nf < 2; ++nf)
#pragma unroll
      for (int ks = 0; ks < 2; ++ks)
        bfr[0][nf][ks] = ld_frag(LB(0, b_half), b_row0 + nf * 16 + lr, ks, lane);
    stage_half(A, IN_F, bm0 + 0, c1k, LA(1, 0), tid);
    PHASE_MID; MFMA_QUAD(0, 0); PHASE_END;

    // ---- P2: quad(0,1) ----
#pragma unroll
    for (int nf = 0; nf < 2; ++nf)
#pragma unroll
      for (int ks = 0; ks < 2; ++ks)
        bfr[1][nf][ks] = ld_frag(LB(0, b_half), b_row0 + 32 + nf * 16 + lr, ks, lane);
    stage_half(A, IN_F, bm0 + 128, c1k, LA(1, 1), tid);
    PHASE_MID; MFMA_QUAD(0, 1); PHASE_END;

    // ---- P3: quad(1,1) ----
#pragma unroll
    for (int mf = 0; mf < 4; ++mf)
#pragma unroll
      for (int ks = 0; ks < 2; ++ks)
        af[mf][ks] = ld_frag(LA(0, wg_m), 64 + mf * 16 + lr, ks, lane);
    stage_half(W, IN_F, bn0 + 0, n0k, LB(0, 0), tid);
    PHASE_MID; MFMA_QUAD(1, 1); PHASE_END;

    // ---- P4: quad(1,0) (all regs) ----
    stage_half(W, IN_F, bn0 + 128, n0k, LB(0, 1), tid);
    PHASE_MID; MFMA_QUAD(1, 0); PHASE_END_VM;

    // ---- P5: quad(0,0) on buf1 ----
#pragma unroll
    for (int mf = 0; mf < 4; ++mf)
#pragma unroll
      for (int ks = 0; ks < 2; ++ks)
        af[mf][ks] = ld_frag(LA(1, wg_m), mf * 16 + lr, ks, lane);
#pragma unroll
    for (int nf = 0; nf < 2; ++nf)
#pragma unroll
      for (int ks = 0; ks < 2; ++ks)
        bfr[0][nf][ks] = ld_frag(LB(1, b_half), b_row0 + nf * 16 + lr, ks, lane);
    stage_half(A, IN_F, bm0 + 0, n0k, LA(0, 0), tid);
    PHASE_MID; MFMA_QUAD(0, 0); PHASE_END;

    // ---- P6: quad(0,1) ----
#pragma unroll
    for (int nf = 0; nf < 2; ++nf)
#pragma unroll
      for (int ks = 0; ks < 2; ++ks)
        bfr[1][nf][ks] = ld_frag(LB(1, b_half), b_row0 + 32 + nf * 16 + lr, ks, lane);
    stage_half(A, IN_F, bm0 + 128, n0k, LA(0, 1), tid);
    PHASE_MID; MFMA_QUAD(0, 1); PHASE_END;

    // ---- P7: quad(1,1) ----
#pragma unroll
    for (int mf = 0; mf < 4; ++mf)
#pragma unroll
      for (int ks = 0; ks < 2; ++ks)
        af[mf][ks] = ld_frag(LA(1, wg_m), 64 + mf * 16 + lr, ks, lane);
    stage_half(W, IN_F, bn0 + 0, n1k, LB(1, 0), tid);
    PHASE_MID; MFMA_QUAD(1, 1); PHASE_END;

    // ---- P8: quad(1,0) (all regs) ----
    stage_half(W, IN_F, bn0 + 128, n1k, LB(1, 1), tid);
    PHASE_MID; MFMA_QUAD(1, 0); PHASE_END_VM;
  }

  // ---- drain outstanding stages before LDS reuse ----
  asm volatile("s_waitcnt vmcnt(0)" ::: "memory");
  __builtin_amdgcn_s_barrier();

  // ---- fused low-rank epilogue ----
  float scl[4], bs_[4];
#pragma unroll
  for (int nf = 0; nf < 4; ++nf) {
    int cg = bn0 + wg_n * 64 + nf * 16 + lr;
    scl[nf] = scale[cg];
    bs_[nf] = bias[cg];
  }

  // regions: H col-subtile s: lds + s*16384 (+8192 for rows 128-255)
  //          L2 col-subtile s: lds + 32768 + s*16384
  stage_half(H, LRANK, bm0 + 0,   0,  lds + 0,     tid);
  stage_half(H, LRANK, bm0 + 128, 0,  lds + 8192,  tid);
  stage_half(H, LRANK, bm0 + 0,   64, lds + 16384, tid);
  stage_half(H, LRANK, bm0 + 128, 64, lds + 24576, tid);
  stage_half(L2, LRANK, bn0 + 0,   0,  lds + 32768, tid);
  stage_half(L2, LRANK, bn0 + 128, 0,  lds + 40960, tid);
  stage_half(L2, LRANK, bn0 + 0,   64, lds + 49152, tid);
  stage_half(L2, LRANK, bn0 + 128, 64, lds + 57344, tid);
  asm volatile("s_waitcnt vmcnt(0)" ::: "memory");
  __builtin_amdgcn_s_barrier();

  // multiplicative pass: acc *= (H·L2m + scale)
#pragma unroll
  for (int nh = 0; nh < 2; ++nh) {
    f32x4 macc[8][2];
#pragma unroll
    for (int m = 0; m < 8; ++m)
#pragma unroll
      for (int j = 0; j < 2; ++j)
#pragma unroll
        for (int v = 0; v < 4; ++v) macc[m][j][v] = 0.f;
#pragma unroll
    for (int kc = 0; kc < 4; ++kc) {
      const u16* Hb = lds + (kc >> 1) * 16384;
      const u16* Lb = lds + 32768 + (kc >> 1) * 16384;
      int ks = kc & 1;
      bf16x8 lf[2];
#pragma unroll
      for (int j = 0; j < 2; ++j) {
        int q = wg_n * 64 + (nh * 2 + j) * 16 + lr;
        lf[j] = ld_frag(Lb + (q >> 7) * 8192, q & 127, ks, lane);
      }
#pragma unroll
      for (int mf = 0; mf < 8; ++mf) {
        int q = wg_m * 128 + mf * 16 + lr;
        bf16x8 hf = ld_frag(Hb + (q >> 7) * 8192, q & 127, ks, lane);
        macc[mf][0] = __builtin_amdgcn_mfma_f32_16x16x32_bf16(hf, lf[0], macc[mf][0], 0, 0, 0);
        macc[mf][1] = __builtin_amdgcn_mfma_f32_16x16x32_bf16(hf, lf[1], macc[mf][1], 0, 0, 0);
      }
    }
#pragma unroll
    for (int mf = 0; mf < 8; ++mf)
#pragma unroll
      for (int j = 0; j < 2; ++j)
#pragma unroll
        for (int v = 0; v < 4; ++v)
          acc[mf][nh * 2 + j][v] *= (macc[mf][j][v] + scl[nh * 2 + j]);
  }

  // restage L2 additive rows
  __builtin_amdgcn_s_barrier();
  stage_half(L2, LRANK, OUT_F + bn0 + 0,   0,  lds + 32768, tid);
  stage_half(L2, LRANK, OUT_F + bn0 + 128, 0,  lds + 40960, tid);
  stage_half(L2, LRANK, OUT_F + bn0 + 0,   64, lds + 49152, tid);
  stage_half(L2, LRANK, OUT_F + bn0 + 128, 64, lds + 57344, tid);
  asm volatile("s_waitcnt vmcnt(0)" ::: "memory");
  __builtin_amdgcn_s_barrier();

  // additive pass: acc += H·L2a + bias
#pragma unroll
  for (int nh = 0; nh < 2; ++nh) {
    f32x4 macc[8][2];
#pragma unroll
    for (int m = 0; m < 8; ++m)
#pragma unroll
      for (int j = 0; j < 2; ++j)
#pragma unroll
        for (int v = 0; v < 4; ++v) macc[m][j][v] = 0.f;
#pragma unroll
    for (int kc = 0; kc < 4; ++kc) {
      const u16* Hb = lds + (kc >> 1) * 16384;
      const u16* Lb = lds + 32768 + (kc >> 1) * 16384;
      int ks = kc & 1;
      bf16x8 lf[2];
#pragma unroll
      for (int j = 0; j < 2; ++j) {
        int q = wg_n * 64 + (nh * 2 + j) * 16 + lr;
        lf[j] = ld_frag(Lb + (q >> 7) * 8192, q & 127, ks, lane);
      }
#pragma unroll
      for (int mf = 0; mf < 8; ++mf) {
        int q = wg_m * 128 + mf * 16 + lr;
        bf16x8 hf = ld_frag(Hb + (q >> 7) * 8192, q & 127, ks, lane);
        macc[mf][0] = __builtin_amdgcn_mfma_f32_16x16x32_bf16(hf, lf[0], macc[mf][0], 0, 0, 0);
        macc[mf][1] = __builtin_amdgcn_mfma_f32_16x16x32_bf16(hf, lf[1], macc[mf][1], 0, 0, 0);
      }
    }
#pragma unroll
    for (int mf = 0; mf < 8; ++mf)
#pragma unroll
      for (int j = 0; j < 2; ++j)
#pragma unroll
        for (int v = 0; v < 4; ++v)
          acc[mf][nh * 2 + j][v] += macc[mf][j][v] + bs_[nh * 2 + j];
  }

  // ---- store ----
#pragma unroll
  for (int mf = 0; mf < 8; ++mf)
#pragma unroll
    for (int nf = 0; nf < 4; ++nf)
#pragma unroll
      for (int v = 0; v < 4; ++v) {
        int rg = bm0 + wg_m * 128 + mf * 16 + (lane >> 4) * 4 + v;
        int cg = bn0 + wg_n * 64 + nf * 16 + lr;
        out[(size_t)rg * OUT_F + cg] = acc[mf][nf][v];
      }
}

// ---------------- launch ----------------

extern "C" void kernel_launch(void* const* d_in, const int* in_sizes, int n_in,
                              void* d_out, int out_size, void* d_ws, size_t ws_size,
                              hipStream_t stream) {
  const float* input = (const float*)d_in[0];
  const int*   zm    = (const int*)d_in[1];
  const float* cb    = (const float*)d_in[2];
  const float* l1    = (const float*)d_in[3];
  const float* l2    = (const float*)d_in[4];
  const float* gs    = (const float*)d_in[5];
  const float* gb    = (const float*)d_in[6];
  const float* scale = (const float*)d_in[7];
  const float* bias  = (const float*)d_in[8];
  float* out = (float*)d_out;

  const size_t OFF_A  = 0;                                        // 64 MiB
  const size_t OFF_W  = OFF_A + (size_t)NTOK * IN_F * 2;          // 32 MiB
  const size_t OFF_L1 = OFF_W + (size_t)OUT_F * IN_F * 2;         // 1 MiB
  const size_t OFF_L2 = OFF_L1 + (size_t)LRANK * IN_F * 2;        // 2 MiB
  const size_t OFF_H  = OFF_L2 + (size_t)2 * OUT_F * LRANK * 2;   // 2 MiB
  const size_t NEED   = OFF_H + (size_t)NTOK * LRANK * 2;
  if (ws_size < NEED) return;

  char* ws = (char*)d_ws;
  u16* A   = (u16*)(ws + OFF_A);
  u16* W   = (u16*)(ws + OFF_W);
  u16* L1b = (u16*)(ws + OFF_L1);
  u16* L2b = (u16*)(ws + OFF_L2);
  u16* H   = (u16*)(ws + OFF_H);

  cvt_bf16_kernel<<<(NTOK * IN_F / 4) / 256, 256, 0, stream>>>(input, A, NTOK * IN_F / 4);
  cvt_bf16_kernel<<<(LRANK * IN_F / 4) / 256, 256, 0, stream>>>(l1, L1b, LRANK * IN_F / 4);
  cvt_bf16_kernel<<<(2 * OUT_F * LRANK / 4) / 256, 256, 0, stream>>>(l2, L2b, 2 * OUT_F * LRANK / 4);
  dequant_kernel<<<(OUT_F * IN_F / 4) / 256, 256, 0, stream>>>(zm, cb, gs, gb, W);

  gemm_hid<<<NTOK / 128, 256, 0, stream>>>(A, L1b, H);

  gemm_main<<<(NTOK / 256) * (OUT_F / 256), 512, 0, stream>>>(A, W, H, L2b, scale, bias, out);
}